// Round 12
// baseline (756.911 us; speedup 1.0000x reference)
//
#include <hip/hip_runtime.h>

typedef _Float16 h8 __attribute__((ext_vector_type(8)));
typedef float f4 __attribute__((ext_vector_type(4)));

#define DEVINL __device__ __forceinline__

// ---------------------------------------------------------------------------
// frag layout (mfma_f32_16x16x32_f16): element (row r, k):
//   frag = (r>>4)*(K>>5) + (k>>5); lane = ((k>>3)&3)*16 + (r&15); idx = k&7.
// One frag = 512 halves = 1 KB = one wave-wide dwordx4.
// ---------------------------------------------------------------------------

DEVINL void gload_lds(const _Float16* g, _Float16* l)
{
    __builtin_amdgcn_global_load_lds(
        (const __attribute__((address_space(1))) void*)g,
        (__attribute__((address_space(3))) void*)l, 16, 0, 0);
}

// ---------------------------------------------------------------------------
// Stage 1: functional kernels (verified rounds 1-3).
// ---------------------------------------------------------------------------

DEVINL void vtb_write(_Float16* vtb, int CB, int p, int d, float v)
{
    size_t off = (((size_t)(p >> 4) * CB) + (d >> 5)) * 512
               + (size_t)(((d >> 3) & 3) * 16 + (p & 15)) * 8 + (d & 7);
    vtb[off] = (_Float16)v;
}

extern "C" __global__ __launch_bounds__(256)
void func_c4_kernel(const float* __restrict__ x, _Float16* __restrict__ vtb,
                    float* __restrict__ V4d)
{
    int wave = threadIdx.x >> 6, lane = threadIdx.x & 63;
    int idx = blockIdx.x * 4 + wave;
    int b = idx >> 11, i = idx & 2047;
    size_t base = (size_t)(b * 2048 + i) * 256;
    float acc = 0.f;
#pragma unroll
    for (int it = 0; it < 4; ++it) acc += x[base + it * 64 + lane];
#pragma unroll
    for (int m = 1; m < 64; m <<= 1) acc += __shfl_xor(acc, m);
    float mean = acc * (1.f / 256.f);
    _Float16* vb = vtb + (size_t)b * 16 * 2048;
    if (lane < 16) vtb_write(vb, 64, lane, i, (lane == 0) ? mean : 0.f);
    if (lane == 0) V4d[b * 2048 + i] = mean;
}

extern "C" __global__ __launch_bounds__(256)
void func_c3_kernel(const float* __restrict__ x, _Float16* __restrict__ vtb)
{
    __shared__ float scr[4][12];
    int wave = threadIdx.x >> 6, lane = threadIdx.x & 63;
    int idx = blockIdx.x * 4 + wave;
    int b = idx >> 10, i = idx & 1023;
    size_t base = (size_t)(b * 1024 + i) * 1024;
    float acc = 0.f;
    for (int it = 0; it < 15; ++it) acc += x[base + it * 64 + lane];
    float vl = x[base + 15 * 64 + lane];
    acc += vl;
    float tr = (lane >= 32) ? vl : 0.f;
    float tcpre = acc;
    float xpre = tr;
#pragma unroll
    for (int m = 2; m < 32; m <<= 1) {
        acc += __shfl_xor(acc, m);
        tr += __shfl_xor(tr, m);
    }
    if ((lane & 31) < 2) {
        int rp = lane >> 5, cp = lane & 1;
        scr[wave][rp * 2 + cp] = acc;
        if (rp == 1) scr[wave][4 + cp] = tr;
    }
    if ((lane & 31) == 31) {
        int rp = lane >> 5;
        scr[wave][6 + rp] = tcpre;
        if (rp == 1) scr[wave][8] = xpre;
    }
    __syncthreads();
    if (lane < 16) {
        float out = 0.f;
        if (lane < 9) {
            int kh = lane / 3, kw = lane - kh * 3;
            int rp = (kh == 1) ? 0 : 1, cp = (kw == 1) ? 0 : 1;
            bool er = (kh == 0), ec = (kw == 0);
            const float* s = scr[wave];
            out = s[rp * 2 + cp];
            if (er) out -= s[4 + cp];
            if (ec) out -= s[6 + rp];
            if (er && ec) out += s[8];
        }
        vtb_write(vtb + (size_t)b * 16 * 1024, 32, lane, i, out);
    }
}

DEVINL float camU(const float* s, int p)
{
    int rc = p / 9, cc = p - rc * 9;
    int kh = rc / 3, kh2 = rc - kh * 3;
    int kw = cc / 3, kw2 = cc - kw * 3;
    int rm = (kh == 1) ? ((kh2 + 3) & 3) : (kh2 + 1);
    int cm = (kw == 1) ? ((kw2 + 3) & 3) : (kw2 + 1);
    bool er = (rc < 4), ec = (cc < 4);
    float u = s[rm * 4 + cm];
    if (er) u -= s[16 + (rm - 1) * 4 + cm];
    if (ec) u -= s[28 + rm * 3 + (cm - 1)];
    if (er && ec) u += s[40 + (rm - 1) * 3 + (cm - 1)];
    return u;
}

extern "C" __global__ __launch_bounds__(256)
void func_c2_kernel(const float* __restrict__ x, _Float16* __restrict__ vtb)
{
    __shared__ float scr[4][52];
    int wave = threadIdx.x >> 6, lane = threadIdx.x & 63;
    int idx = blockIdx.x * 4 + wave;
    int b = idx >> 9, i = idx & 511;
    size_t base = (size_t)(b * 512 + i) * 4096;
    float acc[4] = {0.f, 0.f, 0.f, 0.f};
    float tr[3];
    for (int it = 0; it < 60; it += 4) {
#pragma unroll
        for (int rr = 0; rr < 4; ++rr)
            acc[rr] += x[base + (size_t)(it + rr) * 64 + lane];
    }
    acc[0] += x[base + 60 * 64 + lane];
#pragma unroll
    for (int rr = 1; rr < 4; ++rr) {
        float v = x[base + (size_t)(60 + rr) * 64 + lane];
        acc[rr] += v;
        tr[rr - 1] = v;
    }
    float tcx[4], xr[3];
#pragma unroll
    for (int g = 0; g < 4; ++g) tcx[g] = acc[g];
#pragma unroll
    for (int g = 0; g < 3; ++g) xr[g] = tr[g];
#pragma unroll
    for (int m = 4; m < 64; m <<= 1) {
#pragma unroll
        for (int g = 0; g < 4; ++g) acc[g] += __shfl_xor(acc[g], m);
#pragma unroll
        for (int g = 0; g < 3; ++g) tr[g] += __shfl_xor(tr[g], m);
    }
    if (lane < 4) {
#pragma unroll
        for (int rm = 0; rm < 4; ++rm) scr[wave][rm * 4 + lane] = acc[rm];
#pragma unroll
        for (int rx = 0; rx < 3; ++rx) scr[wave][16 + rx * 4 + lane] = tr[rx];
    }
    if (lane >= 61) {
        int cx = lane - 61;
#pragma unroll
        for (int rm = 0; rm < 4; ++rm) scr[wave][28 + rm * 3 + cx] = tcx[rm];
#pragma unroll
        for (int rx = 0; rx < 3; ++rx) scr[wave][40 + rx * 3 + cx] = xr[rx];
    }
    __syncthreads();
    const float* s = scr[wave];
    _Float16* vb = vtb + (size_t)b * 96 * 512;
    vtb_write(vb, 16, lane, i, camU(s, lane));
    if (lane < 32) {
        int p = 64 + lane;
        vtb_write(vb, 16, p, i, (p < 81) ? camU(s, p) : 0.f);
    }
}

// ---------------------------------------------------------------------------
// Stage 2: repack fp32 row-major -> frag fp16 (generic 16 rows x 256 cols).
// ---------------------------------------------------------------------------
DEVINL void repack_tile(const float* __restrict__ src, _Float16* __restrict__ dst,
                        int K, int grp, int chunk, _Float16 (*T)[264])
{
    int tid = threadIdx.x;
    {
        int row = tid >> 4, t16 = tid & 15;
        const float* s = src + ((size_t)grp * 16 + row) * K + chunk * 256 + t16 * 16;
        float4 a = *(const float4*)(s + 0);
        float4 b = *(const float4*)(s + 4);
        float4 c = *(const float4*)(s + 8);
        float4 d = *(const float4*)(s + 12);
        h8 lo = {(_Float16)a.x, (_Float16)a.y, (_Float16)a.z, (_Float16)a.w,
                 (_Float16)b.x, (_Float16)b.y, (_Float16)b.z, (_Float16)b.w};
        h8 hi = {(_Float16)c.x, (_Float16)c.y, (_Float16)c.z, (_Float16)c.w,
                 (_Float16)d.x, (_Float16)d.y, (_Float16)d.z, (_Float16)d.w};
        *(h8*)&T[row][t16 * 16] = lo;
        *(h8*)&T[row][t16 * 16 + 8] = hi;
    }
    __syncthreads();
    int fl = tid >> 5, idx2 = tid & 31;
    size_t base = (size_t)grp * 16 * K + (size_t)(chunk * 8 + fl) * 512;
#pragma unroll
    for (int rep = 0; rep < 2; ++rep) {
        int idx = idx2 + rep * 32;
        int l16 = idx & 15, quad = idx >> 4;
        h8 v = *(h8*)&T[l16][fl * 32 + quad * 8];
        *(h8*)&dst[base + (size_t)idx * 8] = v;
    }
}

extern "C" __global__ __launch_bounds__(256)
void repack_kernel(const float* __restrict__ c2, const float* __restrict__ c3,
                   const float* __restrict__ c4, _Float16* __restrict__ xb2,
                   _Float16* __restrict__ xb3, _Float16* __restrict__ xb4)
{
    __shared__ _Float16 T[16][264];
    int bid = blockIdx.x;
    const float* src; _Float16* dst; int K, grp, chunk;
    if (bid < 8192) { src = c2; dst = xb2; K = 4096; grp = bid >> 4; chunk = bid & 15; }
    else if (bid < 12288) { int id = bid - 8192; src = c3; dst = xb3; K = 1024; grp = id >> 2; chunk = id & 3; }
    else { src = c4; dst = xb4; K = 256; grp = bid - 12288; chunk = 0; }
    repack_tile(src, dst, K, grp, chunk, T);
}

extern "C" __global__ __launch_bounds__(256)
void repack_w_kernel(const float* __restrict__ w4, const float* __restrict__ w3,
                     const float* __restrict__ w2a, const float* __restrict__ w2b,
                     _Float16* __restrict__ w4f, _Float16* __restrict__ w3f,
                     _Float16* __restrict__ w2af, _Float16* __restrict__ w2bf)
{
    __shared__ _Float16 T[16][264];
    int bid = blockIdx.x;
    const float* src; _Float16* dst; int K, grp, chunk;
    if (bid < 256) { src = w4; dst = w4f; K = 2048; grp = bid >> 3; chunk = bid & 7; }
    else if (bid < 1408) { int t = bid - 256; src = w3; dst = w3f; K = 9216; grp = t / 36; chunk = t - 36 * (t / 36); }
    else if (bid < 1984) { int t = bid - 1408; src = w2a; dst = w2af; K = 4608; grp = t / 18; chunk = t - 18 * (t / 18); }
    else { int t = bid - 1984; src = w2b; dst = w2bf; K = 4608; grp = t / 18; chunk = t - 18 * (t / 18); }
    repack_tile(src, dst, K, grp, chunk, T);
}

// ---------------------------------------------------------------------------
// Stage 3: fused CAM flash. RT=4, 2-wave blocks, 640-block grid, SINGLE-A
// rotation (no anxt): order per iter = [wait vmcnt(4); barrier] -> MFMA(buf
// t, acur) -> load acur<-A(t+1) -> gload(t+2). acur is dead after the MFMA
// so A(t+1) reuses its 16 regs; arch-VGPR demand drops ~16 vs round 10.
// launch_bounds(128,1): allocator unconstrained (up to 512) -> no forced
// spill; at ~240 unified regs HW still fits 2 waves/SIMD.
// vmcnt induction: Q(top of t) = [g(t)x4, a(t)x4, g(t+1)x4]; vmcnt(4)
// retires g(t)+a(t) (both consumed now), keeps g(t+1) in flight. Prologue:
// a(0),g(0),g(1) -> Q(0)=[a0,g0,g1], wait retires a0+g0. Tail: fewer
// outstanding; compiler adds waits for acur uses as needed. Buffer WAR
// (write buf[(t+2)&3] vs reads at t-2) separated by 2 barriers. dt-boundary
// V loads (MODE!=3) drain the queue once per dt - harmless.
// ---------------------------------------------------------------------------
template <int N, int C, int DT, int MODE, int RT>
DEVINL void flashT(const _Float16* __restrict__ xfb, const _Float16* __restrict__ vtb,
                   float* __restrict__ Fout, float* __restrict__ FoutD,
                   _Float16* __restrict__ Wg, float* __restrict__ Sml,
                   const float* __restrict__ gptr, int r0, int c0,
                   _Float16* SB, _Float16* SWw)
{
    static_assert(RT == 4, "vmcnt(4) invariant assumes 4 gload + 4 A loads per wave");
    constexpr int KB = N >> 5;
    constexpr int T = DT * KB;
    const int lane = threadIdx.x & 63;
    const int wave = threadIdx.x >> 6;       // 0..1
    const int l16 = lane & 15, quad = lane >> 4;
    const f4 fz = {0.f, 0.f, 0.f, 0.f};
    const size_t loff = (size_t)lane * 8;
    const int fr = wave * 4;

    const _Float16* Abase = xfb + (size_t)((r0 >> 4) + wave * RT) * KB * 512 + loff;

    f4 accp[RT];
    float m_run[RT][4], l_run[RT][4];
#pragma unroll
    for (int rt = 0; rt < RT; ++rt) {
        accp[rt] = fz;
#pragma unroll
        for (int g = 0; g < 4; ++g) { m_run[rt][g] = -3.0e38f; l_run[rt][g] = 0.f; }
    }

    h8 acur[RT];
    f4 e[RT][8];

    // prologue: A(0) FIRST, then gload(0)->buf0, gload(1)->buf1.
    // Q(0) = [a0 x4, g0 x4, g1 x4] -> vmcnt(4) retires a0+g0.
#pragma unroll
    for (int rt = 0; rt < RT; ++rt)
        acur[rt] = *(const h8*)(Abase + (size_t)(rt * KB) * 512);
    __builtin_amdgcn_sched_barrier(0);
#pragma unroll
    for (int u = 0; u < 4; ++u)
        gload_lds(xfb + (size_t)(((c0 >> 4) + fr + u) * KB + 0) * 512 + loff,
                  SB + ((size_t)(0 * 8 + fr + u) << 9));
    if (T > 1) {
#pragma unroll
        for (int u = 0; u < 4; ++u)
            gload_lds(xfb + (size_t)(((c0 >> 4) + fr + u) * KB + 1) * 512 + loff,
                      SB + ((size_t)(1 * 8 + fr + u) << 9));
    }
    __builtin_amdgcn_sched_barrier(0);

#pragma unroll 4
    for (int t = 0; t < T; ++t) {
        if ((t & (KB - 1)) == 0) {
#pragma unroll
            for (int rt = 0; rt < RT; ++rt)
#pragma unroll
                for (int ct = 0; ct < 8; ++ct) e[rt][ct] = fz;
        }
        asm volatile("s_waitcnt vmcnt(4)" ::: "memory");
        __builtin_amdgcn_s_barrier();
        __builtin_amdgcn_sched_barrier(0);
        {
            const int buf = t & 3;
#pragma unroll
            for (int ct = 0; ct < 8; ++ct) {
                h8 bf = *(const h8*)&SB[((size_t)(buf * 8 + ct) << 9) + loff];
#pragma unroll
                for (int rt = 0; rt < RT; ++rt)
                    e[rt][ct] = __builtin_amdgcn_mfma_f32_16x16x32_f16(acur[rt], bf, e[rt][ct], 0, 0, 0);
            }
        }
        __builtin_amdgcn_sched_barrier(0);
        if (t + 1 < T) {
            int nkb = (t + 1) & (KB - 1);
#pragma unroll
            for (int rt = 0; rt < RT; ++rt)
                acur[rt] = *(const h8*)(Abase + ((size_t)rt * KB + nkb) * 512);
        }
        if (t + 2 < T) {
            int tt = t + 2;
            int nkb = tt & (KB - 1);
            int nd0 = c0 + (tt / KB) * 128;
#pragma unroll
            for (int u = 0; u < 4; ++u)
                gload_lds(xfb + (size_t)(((nd0 >> 4) + fr + u) * KB + nkb) * 512 + loff,
                          SB + ((size_t)((tt & 3) * 8 + fr + u) << 9));
        }
        __builtin_amdgcn_sched_barrier(0);

        if ((t & (KB - 1)) == (KB - 1)) {
            const int dt = t / KB;
            const int d0 = c0 + dt * 128;
            // per-tile softmax (s = -energy)
#pragma unroll
            for (int rt = 0; rt < RT; ++rt) {
                float mx[4];
#pragma unroll
                for (int g = 0; g < 4; ++g) {
                    float v = -e[rt][0][g];
#pragma unroll
                    for (int ct = 1; ct < 8; ++ct) v = fmaxf(v, -e[rt][ct][g]);
                    mx[g] = v;
                }
#pragma unroll
                for (int m = 1; m < 16; m <<= 1)
#pragma unroll
                    for (int g = 0; g < 4; ++g) mx[g] = fmaxf(mx[g], __shfl_xor(mx[g], m));
                float mref[4], al[4];
                if (MODE != 3) {
#pragma unroll
                    for (int g = 0; g < 4; ++g) {
                        float nm = fmaxf(m_run[rt][g], mx[g]);
                        al[g] = __expf(m_run[rt][g] - nm);
                        m_run[rt][g] = nm;
                        mref[g] = nm;
                        accp[rt][g] *= al[g];
                    }
                } else {
#pragma unroll
                    for (int g = 0; g < 4; ++g) mref[g] = mx[g];
                }
                float rs[4] = {0.f, 0.f, 0.f, 0.f};
#pragma unroll
                for (int ct = 0; ct < 8; ++ct) {
#pragma unroll
                    for (int g = 0; g < 4; ++g) {
                        float w = __expf(-e[rt][ct][g] - mref[g]);
                        rs[g] += w;
                        int lane2 = ((ct * 2 + (l16 >> 3)) & 3) * 16 + quad * 4 + g;
                        SWw[((ct >> 1) << 9) + lane2 * 8 + (l16 & 7)] = (_Float16)w;
                    }
                }
#pragma unroll
                for (int kc2 = 0; kc2 < 4; ++kc2) {
                    h8 wa = *(const h8*)&SWw[((size_t)kc2 << 9) + loff];
                    if (MODE == 3) {
                        int tile = (c0 >> 7) + dt;
                        int rfrag = (r0 >> 4) + wave * RT + rt;
                        *(h8*)&Wg[((size_t)((tile * 32 + rfrag) * 4 + kc2) << 9) + loff] = wa;
                    } else {
                        h8 vb = *(const h8*)(vtb + (((size_t)(d0 >> 5) + kc2) << 9) + loff);
                        accp[rt] = __builtin_amdgcn_mfma_f32_16x16x32_f16(wa, vb, accp[rt], 0, 0, 0);
                    }
                }
#pragma unroll
                for (int m = 1; m < 16; m <<= 1)
#pragma unroll
                    for (int g = 0; g < 4; ++g) rs[g] += __shfl_xor(rs[g], m);
                if (MODE == 3) {
                    if (l16 == 0) {
                        int tile = (c0 >> 7) + dt;
#pragma unroll
                        for (int g = 0; g < 4; ++g) {
                            int row = r0 + wave * (16 * RT) + rt * 16 + quad * 4 + g;
                            Sml[((size_t)tile * 512 + row) * 2 + 0] = mref[g];
                            Sml[((size_t)tile * 512 + row) * 2 + 1] = rs[g];
                        }
                    }
                } else {
#pragma unroll
                    for (int g = 0; g < 4; ++g)
                        l_run[rt][g] = l_run[rt][g] * al[g] + rs[g];
                }
            }
        }
    }
    if (MODE == 1) {
        float gam = gptr[0];
#pragma unroll
        for (int rt = 0; rt < RT; ++rt)
#pragma unroll
            for (int g = 0; g < 4; ++g) {
                int row = r0 + wave * (16 * RT) + rt * 16 + quad * 4 + g;
                float ident = (float)vtb[(size_t)(row >> 5) * 512
                               + (size_t)(((row >> 3) & 3) * 16 + l16) * 8 + (row & 7)];
                Fout[(size_t)row * 16 + l16] = gam * (accp[rt][g] / l_run[rt][g]) + ident;
            }
    } else if (MODE == 2) {
        float gam = gptr[0];
        if (l16 == 0) {
#pragma unroll
            for (int rt = 0; rt < RT; ++rt)
#pragma unroll
                for (int g = 0; g < 4; ++g) {
                    int row = r0 + wave * (16 * RT) + rt * 16 + quad * 4 + g;
                    float ident = (float)vtb[(size_t)(row >> 5) * 512
                                   + (size_t)(((row >> 3) & 3) * 16) * 8 + (row & 7)];
                    FoutD[row] = gam * (accp[rt][g] / l_run[rt][g]) + ident;
                }
        }
    }
}

extern "C" __global__ __launch_bounds__(128, 1)
void flash_kernel(const _Float16* __restrict__ xb2, const _Float16* __restrict__ xb3,
                  const _Float16* __restrict__ xb4,
                  const _Float16* __restrict__ V3, const _Float16* __restrict__ V4,
                  _Float16* __restrict__ Wg, float* __restrict__ Sml,
                  float* __restrict__ F3, float* __restrict__ F4d,
                  const float* __restrict__ g3, const float* __restrict__ g4)
{
    __shared__ _Float16 SB[32 * 512];           // 4 buffers x 8 frags = 32 KB
    __shared__ _Float16 SW[2 * 4 * 512];        // 2 waves x 4 KB = 8 KB
    _Float16* SWw = &SW[(threadIdx.x >> 6) * 4 * 512];
    int bid = blockIdx.x;
    // c3 first (256 t-iters/block = longest), then c2, then c4 (tail).
    if (bid < 128) {                        // c3: MODE 1, 8 rb x 16 b
        int t = bid, x = t & 7, u = t >> 3;         // u in [0,16)
        int b = x + 8 * (u & 1), rb = u >> 1;       // rb in [0,8)
        flashT<1024, 1024, 8, 1, 4>(xb3 + (size_t)b * 1024 * 1024, V3 + (size_t)b * 16 * 1024,
                                    F3 + (size_t)b * 1024 * 16, nullptr, nullptr, nullptr, g3,
                                    rb * 128, 0, SB, SWw);
    } else if (bid < 384) {                 // c2: MODE 3, 4 rb x 4 ds x 16 b
        int t = bid - 128, x = t & 7, u = t >> 3;   // u in [0,32)
        int b = x + 8 * (u & 1), unit = u >> 1;
        int rb = unit & 3, ds = unit >> 2;
        flashT<4096, 512, 1, 3, 4>(xb2 + (size_t)b * 512 * 4096, nullptr, nullptr, nullptr,
                                   Wg + (size_t)b * 262144, Sml + (size_t)b * 4096, nullptr,
                                   rb * 128, ds * 128, SB, SWw);
    } else {                                // c4: MODE 2, 16 rb x 16 b
        int t = bid - 384, x = t & 7, u = t >> 3;   // u in [0,32)
        int b = x + 8 * (u & 1), rb = u >> 1;       // rb in [0,16)
        flashT<256, 2048, 16, 2, 4>(xb4 + (size_t)b * 2048 * 256, V4 + (size_t)b * 16 * 2048,
                                    nullptr, F4d + (size_t)b * 2048, nullptr, nullptr, g4,
                                    rb * 128, 0, SB, SWw);
    }
}

// ---------------------------------------------------------------------------
// Stage 4: c2 deferred projection: F2 = g2*(softmax@V2)+V2 from Wg + stats.
// ---------------------------------------------------------------------------
extern "C" __global__ __launch_bounds__(256)
void proj_c2_kernel(const _Float16* __restrict__ Wg, const float* __restrict__ Sml,
                    const _Float16* __restrict__ V2, const float* __restrict__ g2,
                    float* __restrict__ F2)
{
    int b = blockIdx.x >> 2, rb = blockIdx.x & 3;
    int lane = threadIdx.x & 63, wave = threadIdx.x >> 6;
    int l16 = lane & 15, quad = lane >> 4;
    size_t loff = (size_t)lane * 8;
    const _Float16* Wb = Wg + (size_t)b * 262144;
    const float* Sb = Sml + (size_t)b * 4096;
    const _Float16* Vb = V2 + (size_t)b * 96 * 512;
    const f4 fz = {0.f, 0.f, 0.f, 0.f};
    f4 accP[2][6];
    float M[2][4], L[2][4];
#pragma unroll
    for (int rt = 0; rt < 2; ++rt) {
#pragma unroll
        for (int pt = 0; pt < 6; ++pt) accP[rt][pt] = fz;
#pragma unroll
        for (int g = 0; g < 4; ++g) { M[rt][g] = -3.0e38f; L[rt][g] = 0.f; }
    }
    for (int t = 0; t < 4; ++t) {
        f4 tmp[2][6];
#pragma unroll
        for (int rt = 0; rt < 2; ++rt)
#pragma unroll
            for (int pt = 0; pt < 6; ++pt) tmp[rt][pt] = fz;
#pragma unroll
        for (int kb = 0; kb < 4; ++kb) {
            h8 wa[2];
#pragma unroll
            for (int rt = 0; rt < 2; ++rt) {
                int rfrag = rb * 8 + wave * 2 + rt;
                wa[rt] = *(const h8*)&Wb[((size_t)((t * 32 + rfrag) * 4 + kb) << 9) + loff];
            }
#pragma unroll
            for (int pt = 0; pt < 6; ++pt) {
                h8 vb = *(const h8*)&Vb[((size_t)(pt * 16 + t * 4 + kb) << 9) + loff];
#pragma unroll
                for (int rt = 0; rt < 2; ++rt)
                    tmp[rt][pt] = __builtin_amdgcn_mfma_f32_16x16x32_f16(wa[rt], vb, tmp[rt][pt], 0, 0, 0);
            }
        }
#pragma unroll
        for (int rt = 0; rt < 2; ++rt)
#pragma unroll
            for (int g = 0; g < 4; ++g) {
                int row = (rb * 8 + wave * 2 + rt) * 16 + quad * 4 + g;
                float mt = Sb[((size_t)t * 512 + row) * 2 + 0];
                float lt = Sb[((size_t)t * 512 + row) * 2 + 1];
                float nm = fmaxf(M[rt][g], mt);
                float ao = __expf(M[rt][g] - nm);
                float at = __expf(mt - nm);
#pragma unroll
                for (int pt = 0; pt < 6; ++pt)
                    accP[rt][pt][g] = accP[rt][pt][g] * ao + at * tmp[rt][pt][g];
                L[rt][g] = L[rt][g] * ao + at * lt;
                M[rt][g] = nm;
            }
    }
    float gam = g2[0];
#pragma unroll
    for (int rt = 0; rt < 2; ++rt)
#pragma unroll
        for (int pt = 0; pt < 6; ++pt)
#pragma unroll
            for (int g = 0; g < 4; ++g) {
                int row = (rb * 8 + wave * 2 + rt) * 16 + quad * 4 + g;
                int p = pt * 16 + l16;
                float ident = (float)Vb[((size_t)pt * 16 + (row >> 5)) * 512
                               + (size_t)(((row >> 3) & 3) * 16 + (p & 15)) * 8 + (row & 7)];
                F2[((size_t)b * 512 + row) * 96 + p] = gam * (accP[rt][pt][g] / L[rt][g]) + ident;
            }
}

// ---------------------------------------------------------------------------
// Stage 5: gather activations into B-frag fp16 tensors for epilogue GEMMs.
// ---------------------------------------------------------------------------
extern "C" __global__ __launch_bounds__(256)
void gather1_kernel(const float* __restrict__ F2, const float* __restrict__ F3,
                    const float* __restrict__ V4d, const float* __restrict__ F4d,
                    _Float16* __restrict__ G, _Float16* __restrict__ XB3,
                    _Float16* __restrict__ XB4)
{
    int gid = blockIdx.x * 256 + threadIdx.x;
    int lane = gid & 63, fragid = gid >> 6;
    int kq = lane >> 4, n16 = lane & 15;
    _Float16 v[8];
    if (fragid < 1296) {                    // G[(i,k2)][(b,kcol)]
        int nb = fragid / 144, kb = fragid - nb * 144;
        int n = nb * 16 + n16;
        int b = n / 9, kcol = n - b * 9;
        int kh = kcol / 3, kw = kcol - kh * 3;
#pragma unroll
        for (int j = 0; j < 8; ++j) {
            int K = kb * 32 + kq * 8 + j;
            int i = K / 9, k2 = K - i * 9;
            int kh2 = k2 / 3, kw2 = k2 - kh2 * 3;
            int p = (kh * 3 + kh2) * 9 + kw * 3 + kw2;
            v[j] = (_Float16)F2[((size_t)b * 512 + i) * 96 + p];
        }
        *(h8*)&G[((size_t)fragid << 9) + lane * 8] = *(h8*)v;
    } else if (fragid < 1584) {             // XB3[(i,k)][b]
        int kb = fragid - 1296;
#pragma unroll
        for (int j = 0; j < 8; ++j) {
            int K = kb * 32 + kq * 8 + j;
            int i = K / 9, k9 = K - i * 9;
            v[j] = (_Float16)F3[((size_t)n16 * 1024 + i) * 16 + k9];
        }
        *(h8*)&XB3[((size_t)kb << 9) + lane * 8] = *(h8*)v;
    } else {                                // XB4[i][(b,which)]
        int f = fragid - 1584;
        int nb = f >> 6, kb = f & 63;
        const float* src = nb ? F4d : V4d;
#pragma unroll
        for (int j = 0; j < 8; ++j) {
            int i = kb * 32 + kq * 8 + j;
            v[j] = (_Float16)src[(size_t)n16 * 2048 + i];
        }
        *(h8*)&XB4[((size_t)f << 9) + lane * 8] = *(h8*)v;
    }
}

// gather XB2 from V2m split partials (fused 9-way reduce)
extern "C" __global__ __launch_bounds__(256)
void gather2_kernel(const float* __restrict__ Pv, _Float16* __restrict__ XB2)
{
    int gid = blockIdx.x * 256 + threadIdx.x;   // 144 frags x 64 lanes
    int lane = gid & 63, kb = gid >> 6;
    int kq = lane >> 4, b = lane & 15;
    _Float16 v[8];
#pragma unroll
    for (int j = 0; j < 8; ++j) {
        int K = kb * 32 + kq * 8 + j;
        int jj = K / 9, k = K - jj * 9;
        float s = 0.f;
#pragma unroll
        for (int ss = 0; ss < 9; ++ss)
            s += Pv[((size_t)ss * 8192 + (size_t)b * 512 + jj) * 9 + k];
        v[j] = (_Float16)s;
    }
    *(h8*)&XB2[((size_t)kb << 9) + lane * 8] = *(h8*)v;
}

// ---------------------------------------------------------------------------
// Stage 6: epilogue GEMMs (MFMA), split-K for occupancy.
// ---------------------------------------------------------------------------
extern "C" __global__ __launch_bounds__(256)
void ep_gemm1_kernel(const _Float16* __restrict__ w2af, const _Float16* __restrict__ G,
                     const _Float16* __restrict__ w3f, const _Float16* __restrict__ XB3,
                     const _Float16* __restrict__ w4f, const _Float16* __restrict__ XB4,
                     float* __restrict__ Pv, float* __restrict__ Pr3,
                     float* __restrict__ Pr4)
{
    int lane = threadIdx.x & 63, wave = threadIdx.x >> 6;
    int l16 = lane & 15, quad = lane >> 4;
    size_t loff = (size_t)lane * 8;
    const f4 fz = {0.f, 0.f, 0.f, 0.f};
    int bid = blockIdx.x;
    if (bid < 72) {                         // V2m partials: 32 mt x 9 splits
        int unit = bid * 4 + wave;          // [0,288)
        int mt = unit & 31, s = unit >> 5;
        f4 acc[9];
#pragma unroll
        for (int nb = 0; nb < 9; ++nb) acc[nb] = fz;
#pragma unroll 2
        for (int kf = s * 16; kf < s * 16 + 16; ++kf) {
            h8 a = *(const h8*)&w2af[(((size_t)(mt * 144 + kf)) << 9) + loff];
#pragma unroll
            for (int nb = 0; nb < 9; ++nb) {
                h8 bfr = *(const h8*)&G[(((size_t)(nb * 144 + kf)) << 9) + loff];
                acc[nb] = __builtin_amdgcn_mfma_f32_16x16x32_f16(a, bfr, acc[nb], 0, 0, 0);
            }
        }
#pragma unroll
        for (int nb = 0; nb < 9; ++nb)
#pragma unroll
            for (int g = 0; g < 4; ++g) {
                int j = mt * 16 + quad * 4 + g;
                int n = nb * 16 + l16;
                int b = n / 9, k = n - b * 9;
                Pv[((size_t)s * 8192 + (size_t)b * 512 + j) * 9 + k] = acc[nb][g];
            }
    } else if (bid < 216) {                 // raw3 partials: 32 mt x 18 splits
        int unit = (bid - 72) * 4 + wave;   // [0,576)
        int mt = unit & 31, s = unit >> 5;
        f4 acc = fz;
#pragma unroll 4
        for (int kf = s * 16; kf < s * 16 + 16; ++kf) {
            h8 a = *(const h8*)&w3f[(((size_t)(mt * 288 + kf)) << 9) + loff];
            h8 bfr = *(const h8*)&XB3[((size_t)kf << 9) + loff];
            acc = __builtin_amdgcn_mfma_f32_16x16x32_f16(a, bfr, acc, 0, 0, 0);
        }
#pragma unroll
        for (int g = 0; g < 4; ++g)
            Pr3[(size_t)(s * 512 + mt * 16 + quad * 4 + g) * 16 + l16] = acc[g];
    } else {                                // raw4 partials: 32 mt x 8 splits
        int unit = (bid - 216) * 4 + wave;  // [0,256)
        int mt = unit & 31, s = unit >> 5;
        f4 acc[2] = {fz, fz};
#pragma unroll 2
        for (int kf = s * 8; kf < s * 8 + 8; ++kf) {
            h8 a = *(const h8*)&w4f[(((size_t)(mt * 64 + kf)) << 9) + loff];
#pragma unroll
            for (int nb = 0; nb < 2; ++nb) {
                h8 bfr = *(const h8*)&XB4[(((size_t)(nb * 64 + kf)) << 9) + loff];
                acc[nb] = __builtin_amdgcn_mfma_f32_16x16x32_f16(a, bfr, acc[nb], 0, 0, 0);
            }
        }
#pragma unroll
        for (int nb = 0; nb < 2; ++nb)
#pragma unroll
            for (int g = 0; g < 4; ++g)
                Pr4[((size_t)s * 1024 + (size_t)nb * 512 + mt * 16 + quad * 4 + g) * 16 + l16] = acc[nb][g];
    }
}

extern "C" __global__ __launch_bounds__(256)
void ep_gemm2_kernel(const _Float16* __restrict__ w2bf, const _Float16* __restrict__ XB2,
                     float* __restrict__ Pr2)
{
    int lane = threadIdx.x & 63, wave = threadIdx.x >> 6;
    int l16 = lane & 15, quad = lane >> 4;
    size_t loff = (size_t)lane * 8;
    int unit = blockIdx.x * 4 + wave;       // [0,288): 32 mt x 9 splits
    int mt = unit & 31, s = unit >> 5;
    f4 acc = {0.f, 0.f, 0.f, 0.f};
#pragma unroll 4
    for (int kf = s * 16; kf < s * 16 + 16; ++kf) {
        h8 a = *(const h8*)&w2bf[(((size_t)(mt * 144 + kf)) << 9) + loff];
        h8 bfr = *(const h8*)&XB2[((size_t)kf << 9) + loff];
        acc = __builtin_amdgcn_mfma_f32_16x16x32_f16(a, bfr, acc, 0, 0, 0);
    }
#pragma unroll
    for (int g = 0; g < 4; ++g)
        Pr2[(size_t)(s * 512 + mt * 16 + quad * 4 + g) * 16 + l16] = acc[g];
}

// ---------------------------------------------------------------------------
// Stage 7: PF assembly (sums split partials) + FC, fused.
// ---------------------------------------------------------------------------
extern "C" __global__ __launch_bounds__(256)
void final_kernel(const float* __restrict__ Pr2, const float* __restrict__ Pr3,
                  const float* __restrict__ Pr4, const float* __restrict__ V4d,
                  const float* __restrict__ b4, const float* __restrict__ b2b,
                  const float* __restrict__ fcw, const float* __restrict__ fcb,
                  float* __restrict__ out)
{
    __shared__ float pf[3584];
    __shared__ float r0s[256], r1s[256];
    int b = blockIdx.x, tid = threadIdx.x;
    for (int o = tid; o < 512; o += 256) {
        float pd = 0.f, pa = 0.f;
#pragma unroll
        for (int s = 0; s < 8; ++s) {
            pd += Pr4[(size_t)(s * 1024 + o) * 16 + b];
            pa += Pr4[(size_t)(s * 1024 + 512 + o) * 16 + b];
        }
        float r3 = 0.f;
#pragma unroll
        for (int s = 0; s < 18; ++s) r3 += Pr3[(size_t)(s * 512 + o) * 16 + b];
        float r2 = 0.f;
#pragma unroll
        for (int s = 0; s < 9; ++s) r2 += Pr2[(size_t)(s * 512 + o) * 16 + b];
        float pd4 = pd + b4[o];
        pf[1024 + o] = pa + b4[o] + pd4;
        pf[512 + o] = r3 * (1.f / 256.f) + pd4;
        pf[o] = r2 * (1.f / 256.f) + b2b[o] + pd4;
    }
    for (int i = tid; i < 2048; i += 256) pf[1536 + i] = V4d[(size_t)b * 2048 + i];
    __syncthreads();
    float p0 = 0.f, p1 = 0.f;
    for (int k = tid; k < 3584; k += 256) {
        float f = pf[k];
        p0 += fcw[k] * f;
        p1 += fcw[3584 + k] * f;
    }
    r0s[tid] = p0;
    r1s[tid] = p1;
    __syncthreads();
    for (int s = 128; s > 0; s >>= 1) {
        if (tid < s) { r0s[tid] += r0s[tid + s]; r1s[tid] += r1s[tid + s]; }
        __syncthreads();
    }
    if (tid == 0) {
        out[b * 2 + 0] = r0s[0] + fcb[0];
        out[b * 2 + 1] = r1s[0] + fcb[1];
    }
}

// ---------------------------------------------------------------------------

extern "C" void kernel_launch(void* const* d_in, const int* in_sizes, int n_in,
                              void* d_out, int out_size, void* d_ws, size_t ws_size,
                              hipStream_t stream)
{
    const float* c2 = (const float*)d_in[0];
    const float* c3 = (const float*)d_in[1];
    const float* c4 = (const float*)d_in[2];
    const float* w4 = (const float*)d_in[3];
    const float* b4 = (const float*)d_in[4];
    const float* w3 = (const float*)d_in[5];
    const float* w2a = (const float*)d_in[6];
    const float* w2b = (const float*)d_in[7];
    const float* b2b = (const float*)d_in[8];
    const float* g2 = (const float*)d_in[9];
    const float* g3 = (const float*)d_in[10];
    const float* g4 = (const float*)d_in[11];
    const float* fcw = (const float*)d_in[12];
    const float* fcb = (const float*)d_in[13];
    float* out = (float*)d_out;

    char* ws = (char*)d_ws;
    size_t off = 0;
    auto carve = [&](size_t bytes) -> char* {
        char* p = ws + off;
        off += (bytes + 255) & ~(size_t)255;
        return p;
    };
    _Float16* xb2 = (_Float16*)carve(67108864);
    _Float16* xb3 = (_Float16*)carve(33554432);
    _Float16* xb4 = (_Float16*)carve(16777216);
    _Float16* V2 = (_Float16*)carve(1572864);
    _Float16* V3 = (_Float16*)carve(524288);
    _Float16* V4 = (_Float16*)carve(1048576);
    float* V4d = (float*)carve(131072);
    _Float16* Wg = (_Float16*)carve(8388608);
    float* Sml = (float*)carve(262144);
    float* F3 = (float*)carve(1048576);
    float* F4d = (float*)carve(131072);
    if (ws_size < off) return;  // workspace too small: fail visibly, no OOB

    // post-flash buffers alias the (then-dead) xb2 region (~31 MB < 64 MB)
    char* al = (char*)xb2;
    auto sub = [&](size_t bytes) -> char* {
        char* p = al;
        al += (bytes + 255) & ~(size_t)255;
        return p;
    };
    float* F2 = (float*)sub(3145728);
    _Float16* w4f = (_Float16*)sub(2097152);
    _Float16* w3f = (_Float16*)sub(9437184);
    _Float16* w2af = (_Float16*)sub(4718592);
    _Float16* w2bf = (_Float16*)sub(4718592);
    _Float16* G = (_Float16*)sub(1327104);
    _Float16* XB3 = (_Float16*)sub(294912);
    _Float16* XB4 = (_Float16*)sub(131072);
    float* Pv = (float*)sub(2654208);
    _Float16* XB2 = (_Float16*)sub(147456);
    float* Pr2 = (float*)sub(294912);
    float* Pr3 = (float*)sub(589824);
    float* Pr4 = (float*)sub(524288);

    repack_kernel<<<14336, 256, 0, stream>>>(c2, c3, c4, xb2, xb3, xb4);
    func_c2_kernel<<<2048, 256, 0, stream>>>(c2, V2);
    func_c3_kernel<<<4096, 256, 0, stream>>>(c3, V3);
    func_c4_kernel<<<8192, 256, 0, stream>>>(c4, V4, V4d);
    flash_kernel<<<640, 128, 0, stream>>>(xb2, xb3, xb4, V3, V4, Wg, Sml,
                                          F3, F4d, g3, g4);
    repack_w_kernel<<<2560, 256, 0, stream>>>(w4, w3, w2a, w2b, w4f, w3f, w2af, w2bf);
    proj_c2_kernel<<<64, 256, 0, stream>>>(Wg, Sml, V2, g2, F2);
    gather1_kernel<<<428, 256, 0, stream>>>(F2, F3, V4d, F4d, G, XB3, XB4);
    ep_gemm1_kernel<<<280, 256, 0, stream>>>(w2af, G, w3f, XB3, w4f, XB4,
                                             Pv, Pr3, Pr4);
    gather2_kernel<<<36, 256, 0, stream>>>(Pv, XB2);
    ep_gemm2_kernel<<<72, 256, 0, stream>>>(w2bf, XB2, Pr2);
    final_kernel<<<16, 256, 0, stream>>>(Pr2, Pr3, Pr4, V4d, b4, b2b,
                                         fcw, fcb, out);
}

// Round 13
// 654.173 us; speedup vs baseline: 1.1571x; 1.1571x over previous
//
#include <hip/hip_runtime.h>

typedef _Float16 h8 __attribute__((ext_vector_type(8)));
typedef float f4 __attribute__((ext_vector_type(4)));

#define DEVINL __device__ __forceinline__

// ---------------------------------------------------------------------------
// frag layout (mfma_f32_16x16x32_f16): element (row r, k):
//   frag = (r>>4)*(K>>5) + (k>>5); lane = ((k>>3)&3)*16 + (r&15); idx = k&7.
// One frag = 512 halves = 1 KB = one wave-wide dwordx4.
// ---------------------------------------------------------------------------

DEVINL void gload_lds(const _Float16* g, _Float16* l)
{
    __builtin_amdgcn_global_load_lds(
        (const __attribute__((address_space(1))) void*)g,
        (__attribute__((address_space(3))) void*)l, 16, 0, 0);
}

// ---------------------------------------------------------------------------
// Stage 1: functional kernels (verified rounds 1-3).
// ---------------------------------------------------------------------------

DEVINL void vtb_write(_Float16* vtb, int CB, int p, int d, float v)
{
    size_t off = (((size_t)(p >> 4) * CB) + (d >> 5)) * 512
               + (size_t)(((d >> 3) & 3) * 16 + (p & 15)) * 8 + (d & 7);
    vtb[off] = (_Float16)v;
}

extern "C" __global__ __launch_bounds__(256)
void func_c4_kernel(const float* __restrict__ x, _Float16* __restrict__ vtb,
                    float* __restrict__ V4d)
{
    int wave = threadIdx.x >> 6, lane = threadIdx.x & 63;
    int idx = blockIdx.x * 4 + wave;
    int b = idx >> 11, i = idx & 2047;
    size_t base = (size_t)(b * 2048 + i) * 256;
    float acc = 0.f;
#pragma unroll
    for (int it = 0; it < 4; ++it) acc += x[base + it * 64 + lane];
#pragma unroll
    for (int m = 1; m < 64; m <<= 1) acc += __shfl_xor(acc, m);
    float mean = acc * (1.f / 256.f);
    _Float16* vb = vtb + (size_t)b * 16 * 2048;
    if (lane < 16) vtb_write(vb, 64, lane, i, (lane == 0) ? mean : 0.f);
    if (lane == 0) V4d[b * 2048 + i] = mean;
}

extern "C" __global__ __launch_bounds__(256)
void func_c3_kernel(const float* __restrict__ x, _Float16* __restrict__ vtb)
{
    __shared__ float scr[4][12];
    int wave = threadIdx.x >> 6, lane = threadIdx.x & 63;
    int idx = blockIdx.x * 4 + wave;
    int b = idx >> 10, i = idx & 1023;
    size_t base = (size_t)(b * 1024 + i) * 1024;
    float acc = 0.f;
    for (int it = 0; it < 15; ++it) acc += x[base + it * 64 + lane];
    float vl = x[base + 15 * 64 + lane];
    acc += vl;
    float tr = (lane >= 32) ? vl : 0.f;
    float tcpre = acc;
    float xpre = tr;
#pragma unroll
    for (int m = 2; m < 32; m <<= 1) {
        acc += __shfl_xor(acc, m);
        tr += __shfl_xor(tr, m);
    }
    if ((lane & 31) < 2) {
        int rp = lane >> 5, cp = lane & 1;
        scr[wave][rp * 2 + cp] = acc;
        if (rp == 1) scr[wave][4 + cp] = tr;
    }
    if ((lane & 31) == 31) {
        int rp = lane >> 5;
        scr[wave][6 + rp] = tcpre;
        if (rp == 1) scr[wave][8] = xpre;
    }
    __syncthreads();
    if (lane < 16) {
        float out = 0.f;
        if (lane < 9) {
            int kh = lane / 3, kw = lane - kh * 3;
            int rp = (kh == 1) ? 0 : 1, cp = (kw == 1) ? 0 : 1;
            bool er = (kh == 0), ec = (kw == 0);
            const float* s = scr[wave];
            out = s[rp * 2 + cp];
            if (er) out -= s[4 + cp];
            if (ec) out -= s[6 + rp];
            if (er && ec) out += s[8];
        }
        vtb_write(vtb + (size_t)b * 16 * 1024, 32, lane, i, out);
    }
}

DEVINL float camU(const float* s, int p)
{
    int rc = p / 9, cc = p - rc * 9;
    int kh = rc / 3, kh2 = rc - kh * 3;
    int kw = cc / 3, kw2 = cc - kw * 3;
    int rm = (kh == 1) ? ((kh2 + 3) & 3) : (kh2 + 1);
    int cm = (kw == 1) ? ((kw2 + 3) & 3) : (kw2 + 1);
    bool er = (rc < 4), ec = (cc < 4);
    float u = s[rm * 4 + cm];
    if (er) u -= s[16 + (rm - 1) * 4 + cm];
    if (ec) u -= s[28 + rm * 3 + (cm - 1)];
    if (er && ec) u += s[40 + (rm - 1) * 3 + (cm - 1)];
    return u;
}

extern "C" __global__ __launch_bounds__(256)
void func_c2_kernel(const float* __restrict__ x, _Float16* __restrict__ vtb)
{
    __shared__ float scr[4][52];
    int wave = threadIdx.x >> 6, lane = threadIdx.x & 63;
    int idx = blockIdx.x * 4 + wave;
    int b = idx >> 9, i = idx & 511;
    size_t base = (size_t)(b * 512 + i) * 4096;
    float acc[4] = {0.f, 0.f, 0.f, 0.f};
    float tr[3];
    for (int it = 0; it < 60; it += 4) {
#pragma unroll
        for (int rr = 0; rr < 4; ++rr)
            acc[rr] += x[base + (size_t)(it + rr) * 64 + lane];
    }
    acc[0] += x[base + 60 * 64 + lane];
#pragma unroll
    for (int rr = 1; rr < 4; ++rr) {
        float v = x[base + (size_t)(60 + rr) * 64 + lane];
        acc[rr] += v;
        tr[rr - 1] = v;
    }
    float tcx[4], xr[3];
#pragma unroll
    for (int g = 0; g < 4; ++g) tcx[g] = acc[g];
#pragma unroll
    for (int g = 0; g < 3; ++g) xr[g] = tr[g];
#pragma unroll
    for (int m = 4; m < 64; m <<= 1) {
#pragma unroll
        for (int g = 0; g < 4; ++g) acc[g] += __shfl_xor(acc[g], m);
#pragma unroll
        for (int g = 0; g < 3; ++g) tr[g] += __shfl_xor(tr[g], m);
    }
    if (lane < 4) {
#pragma unroll
        for (int rm = 0; rm < 4; ++rm) scr[wave][rm * 4 + lane] = acc[rm];
#pragma unroll
        for (int rx = 0; rx < 3; ++rx) scr[wave][16 + rx * 4 + lane] = tr[rx];
    }
    if (lane >= 61) {
        int cx = lane - 61;
#pragma unroll
        for (int rm = 0; rm < 4; ++rm) scr[wave][28 + rm * 3 + cx] = tcx[rm];
#pragma unroll
        for (int rx = 0; rx < 3; ++rx) scr[wave][40 + rx * 3 + cx] = xr[rx];
    }
    __syncthreads();
    const float* s = scr[wave];
    _Float16* vb = vtb + (size_t)b * 96 * 512;
    vtb_write(vb, 16, lane, i, camU(s, lane));
    if (lane < 32) {
        int p = 64 + lane;
        vtb_write(vb, 16, p, i, (p < 81) ? camU(s, p) : 0.f);
    }
}

// ---------------------------------------------------------------------------
// Stage 2: repack fp32 row-major -> frag fp16 (generic 16 rows x 256 cols).
// ---------------------------------------------------------------------------
DEVINL void repack_tile(const float* __restrict__ src, _Float16* __restrict__ dst,
                        int K, int grp, int chunk, _Float16 (*T)[264])
{
    int tid = threadIdx.x;
    {
        int row = tid >> 4, t16 = tid & 15;
        const float* s = src + ((size_t)grp * 16 + row) * K + chunk * 256 + t16 * 16;
        float4 a = *(const float4*)(s + 0);
        float4 b = *(const float4*)(s + 4);
        float4 c = *(const float4*)(s + 8);
        float4 d = *(const float4*)(s + 12);
        h8 lo = {(_Float16)a.x, (_Float16)a.y, (_Float16)a.z, (_Float16)a.w,
                 (_Float16)b.x, (_Float16)b.y, (_Float16)b.z, (_Float16)b.w};
        h8 hi = {(_Float16)c.x, (_Float16)c.y, (_Float16)c.z, (_Float16)c.w,
                 (_Float16)d.x, (_Float16)d.y, (_Float16)d.z, (_Float16)d.w};
        *(h8*)&T[row][t16 * 16] = lo;
        *(h8*)&T[row][t16 * 16 + 8] = hi;
    }
    __syncthreads();
    int fl = tid >> 5, idx2 = tid & 31;
    size_t base = (size_t)grp * 16 * K + (size_t)(chunk * 8 + fl) * 512;
#pragma unroll
    for (int rep = 0; rep < 2; ++rep) {
        int idx = idx2 + rep * 32;
        int l16 = idx & 15, quad = idx >> 4;
        h8 v = *(h8*)&T[l16][fl * 32 + quad * 8];
        *(h8*)&dst[base + (size_t)idx * 8] = v;
    }
}

extern "C" __global__ __launch_bounds__(256)
void repack_kernel(const float* __restrict__ c2, const float* __restrict__ c3,
                   const float* __restrict__ c4, _Float16* __restrict__ xb2,
                   _Float16* __restrict__ xb3, _Float16* __restrict__ xb4)
{
    __shared__ _Float16 T[16][264];
    int bid = blockIdx.x;
    const float* src; _Float16* dst; int K, grp, chunk;
    if (bid < 8192) { src = c2; dst = xb2; K = 4096; grp = bid >> 4; chunk = bid & 15; }
    else if (bid < 12288) { int id = bid - 8192; src = c3; dst = xb3; K = 1024; grp = id >> 2; chunk = id & 3; }
    else { src = c4; dst = xb4; K = 256; grp = bid - 12288; chunk = 0; }
    repack_tile(src, dst, K, grp, chunk, T);
}

extern "C" __global__ __launch_bounds__(256)
void repack_w_kernel(const float* __restrict__ w4, const float* __restrict__ w3,
                     const float* __restrict__ w2a, const float* __restrict__ w2b,
                     _Float16* __restrict__ w4f, _Float16* __restrict__ w3f,
                     _Float16* __restrict__ w2af, _Float16* __restrict__ w2bf)
{
    __shared__ _Float16 T[16][264];
    int bid = blockIdx.x;
    const float* src; _Float16* dst; int K, grp, chunk;
    if (bid < 256) { src = w4; dst = w4f; K = 2048; grp = bid >> 3; chunk = bid & 7; }
    else if (bid < 1408) { int t = bid - 256; src = w3; dst = w3f; K = 9216; grp = t / 36; chunk = t - 36 * (t / 36); }
    else if (bid < 1984) { int t = bid - 1408; src = w2a; dst = w2af; K = 4608; grp = t / 18; chunk = t - 18 * (t / 18); }
    else { int t = bid - 1984; src = w2b; dst = w2bf; K = 4608; grp = t / 18; chunk = t - 18 * (t / 18); }
    repack_tile(src, dst, K, grp, chunk, T);
}

// ---------------------------------------------------------------------------
// Stage 3: fused CAM flash, depth-2 counted-vmcnt pipeline, 4 LDS buffers.
// (Round-7 configuration — best measured: flash 200us, e2e 664us.)
// Fused tile loop t in [0, DT*KB). Issue order per iteration (pinned by
// sched_barrier): [wait vmcnt(2); barrier] -> anxt A(t+1) -> vbs (dt start,
// MODE!=3) -> gload(t+2) -> MFMA buf[t&3]. Steady-state outstanding at the
// top wait, oldest-first: [g(t)x2, a(t)x2, (vbs), g(t+1)x2, g(t+2)x2];
// vmcnt(2) retires through a(t) and leaves both prefetched gload pairs in
// flight -> ~2 iterations of HBM latency cover. V loads hoisted to regs at
// dt start so their consumption never forces a vmcnt(0) drain. Buffer WAR
// hazard (write buf[(t+2)&3] vs reads at t-2) separated by 2 barriers.
// RT=4 variants (rounds 8-12) all fail: 128 acc regs + pipeline state
// either spills (WRITE_SIZE 61-105MB) or serializes A-loads (HBM 650GB/s).
// ---------------------------------------------------------------------------
template <int N, int C, int DT, int MODE, int RT>
DEVINL void flashT(const _Float16* __restrict__ xfb, const _Float16* __restrict__ vtb,
                   float* __restrict__ Fout, float* __restrict__ FoutD,
                   _Float16* __restrict__ Wg, float* __restrict__ Sml,
                   const float* __restrict__ gptr, int r0, int c0,
                   _Float16* SB, _Float16* SWw)
{
    static_assert(RT == 2, "vmcnt invariant assumes 2 A loads per wave");
    constexpr int KB = N >> 5;
    constexpr int T = DT * KB;
    const int lane = threadIdx.x & 63;
    const int wave = threadIdx.x >> 6;
    const int l16 = lane & 15, quad = lane >> 4;
    const f4 fz = {0.f, 0.f, 0.f, 0.f};
    const size_t loff = (size_t)lane * 8;
    const int fr = wave * 2;

    const _Float16* Abase = xfb + (size_t)((r0 >> 4) + wave * RT) * KB * 512 + loff;

    f4 accp[RT];
    float m_run[RT][4], l_run[RT][4];
#pragma unroll
    for (int rt = 0; rt < RT; ++rt) {
        accp[rt] = fz;
#pragma unroll
        for (int g = 0; g < 4; ++g) { m_run[rt][g] = -3.0e38f; l_run[rt][g] = 0.f; }
    }

    h8 acur[RT], anxt[RT], vbs[4];
    f4 e[RT][8];

    // prologue: A(0) FIRST (oldest in vmcnt), then gload(0)->buf0, gload(1)->buf1.
#pragma unroll
    for (int rt = 0; rt < RT; ++rt)
        acur[rt] = *(const h8*)(Abase + (size_t)(rt * KB) * 512);
    __builtin_amdgcn_sched_barrier(0);
#pragma unroll
    for (int u = 0; u < 2; ++u)
        gload_lds(xfb + (size_t)(((c0 >> 4) + fr + u) * KB + 0) * 512 + loff,
                  SB + ((size_t)(0 * 8 + fr + u) << 9));
    if (T > 1) {
#pragma unroll
        for (int u = 0; u < 2; ++u)
            gload_lds(xfb + (size_t)(((c0 >> 4) + fr + u) * KB + 1) * 512 + loff,
                      SB + ((size_t)(1 * 8 + fr + u) << 9));
    }
    __builtin_amdgcn_sched_barrier(0);

#pragma unroll 4
    for (int t = 0; t < T; ++t) {
        if ((t & (KB - 1)) == 0) {
#pragma unroll
            for (int rt = 0; rt < RT; ++rt)
#pragma unroll
                for (int ct = 0; ct < 8; ++ct) e[rt][ct] = fz;
        }
        asm volatile("s_waitcnt vmcnt(2)" ::: "memory");
        __builtin_amdgcn_s_barrier();
        __builtin_amdgcn_sched_barrier(0);
        if (t + 1 < T) {
            int nkb = (t + 1) & (KB - 1);
#pragma unroll
            for (int rt = 0; rt < RT; ++rt)
                anxt[rt] = *(const h8*)(Abase + ((size_t)rt * KB + nkb) * 512);
        }
        if (MODE != 3 && (t & (KB - 1)) == 0) {
            int d0 = c0 + (t / KB) * 128;
#pragma unroll
            for (int k2 = 0; k2 < 4; ++k2)
                vbs[k2] = *(const h8*)(vtb + (((size_t)(d0 >> 5) + k2) << 9) + loff);
        }
        __builtin_amdgcn_sched_barrier(0);
        if (t + 2 < T) {
            int tt = t + 2;
            int nkb = tt & (KB - 1);
            int nd0 = c0 + (tt / KB) * 128;
#pragma unroll
            for (int u = 0; u < 2; ++u)
                gload_lds(xfb + (size_t)(((nd0 >> 4) + fr + u) * KB + nkb) * 512 + loff,
                          SB + ((size_t)((tt & 3) * 8 + fr + u) << 9));
        }
        __builtin_amdgcn_sched_barrier(0);
        {
            const int buf = t & 3;
#pragma unroll
            for (int ct = 0; ct < 8; ++ct) {
                h8 bf = *(const h8*)&SB[((size_t)(buf * 8 + ct) << 9) + loff];
#pragma unroll
                for (int rt = 0; rt < RT; ++rt)
                    e[rt][ct] = __builtin_amdgcn_mfma_f32_16x16x32_f16(acur[rt], bf, e[rt][ct], 0, 0, 0);
            }
        }
#pragma unroll
        for (int rt = 0; rt < RT; ++rt) acur[rt] = anxt[rt];

        if ((t & (KB - 1)) == (KB - 1)) {
            const int dt = t / KB;
            // per-tile softmax (s = -energy)
#pragma unroll
            for (int rt = 0; rt < RT; ++rt) {
                float mx[4];
#pragma unroll
                for (int g = 0; g < 4; ++g) {
                    float v = -e[rt][0][g];
#pragma unroll
                    for (int ct = 1; ct < 8; ++ct) v = fmaxf(v, -e[rt][ct][g]);
                    mx[g] = v;
                }
#pragma unroll
                for (int m = 1; m < 16; m <<= 1)
#pragma unroll
                    for (int g = 0; g < 4; ++g) mx[g] = fmaxf(mx[g], __shfl_xor(mx[g], m));
                float mref[4], al[4];
                if (MODE != 3) {
#pragma unroll
                    for (int g = 0; g < 4; ++g) {
                        float nm = fmaxf(m_run[rt][g], mx[g]);
                        al[g] = __expf(m_run[rt][g] - nm);
                        m_run[rt][g] = nm;
                        mref[g] = nm;
                        accp[rt][g] *= al[g];
                    }
                } else {
#pragma unroll
                    for (int g = 0; g < 4; ++g) mref[g] = mx[g];
                }
                float rs[4] = {0.f, 0.f, 0.f, 0.f};
#pragma unroll
                for (int ct = 0; ct < 8; ++ct) {
#pragma unroll
                    for (int g = 0; g < 4; ++g) {
                        float w = __expf(-e[rt][ct][g] - mref[g]);
                        rs[g] += w;
                        int lane2 = ((ct * 2 + (l16 >> 3)) & 3) * 16 + quad * 4 + g;
                        SWw[((ct >> 1) << 9) + lane2 * 8 + (l16 & 7)] = (_Float16)w;
                    }
                }
#pragma unroll
                for (int kc2 = 0; kc2 < 4; ++kc2) {
                    h8 wa = *(const h8*)&SWw[((size_t)kc2 << 9) + loff];
                    if (MODE == 3) {
                        int tile = (c0 >> 7) + dt;
                        int rfrag = (r0 >> 4) + wave * RT + rt;
                        *(h8*)&Wg[((size_t)((tile * 32 + rfrag) * 4 + kc2) << 9) + loff] = wa;
                    } else {
                        accp[rt] = __builtin_amdgcn_mfma_f32_16x16x32_f16(wa, vbs[kc2], accp[rt], 0, 0, 0);
                    }
                }
#pragma unroll
                for (int m = 1; m < 16; m <<= 1)
#pragma unroll
                    for (int g = 0; g < 4; ++g) rs[g] += __shfl_xor(rs[g], m);
                if (MODE == 3) {
                    if (l16 == 0) {
                        int tile = (c0 >> 7) + dt;
#pragma unroll
                        for (int g = 0; g < 4; ++g) {
                            int row = r0 + wave * (16 * RT) + rt * 16 + quad * 4 + g;
                            Sml[((size_t)tile * 512 + row) * 2 + 0] = mref[g];
                            Sml[((size_t)tile * 512 + row) * 2 + 1] = rs[g];
                        }
                    }
                } else {
#pragma unroll
                    for (int g = 0; g < 4; ++g)
                        l_run[rt][g] = l_run[rt][g] * al[g] + rs[g];
                }
            }
        }
    }
    if (MODE == 1) {
        float gam = gptr[0];
#pragma unroll
        for (int rt = 0; rt < RT; ++rt)
#pragma unroll
            for (int g = 0; g < 4; ++g) {
                int row = r0 + wave * (16 * RT) + rt * 16 + quad * 4 + g;
                float ident = (float)vtb[(size_t)(row >> 5) * 512
                               + (size_t)(((row >> 3) & 3) * 16 + l16) * 8 + (row & 7)];
                Fout[(size_t)row * 16 + l16] = gam * (accp[rt][g] / l_run[rt][g]) + ident;
            }
    } else if (MODE == 2) {
        float gam = gptr[0];
        if (l16 == 0) {
#pragma unroll
            for (int rt = 0; rt < RT; ++rt)
#pragma unroll
                for (int g = 0; g < 4; ++g) {
                    int row = r0 + wave * (16 * RT) + rt * 16 + quad * 4 + g;
                    float ident = (float)vtb[(size_t)(row >> 5) * 512
                                   + (size_t)(((row >> 3) & 3) * 16) * 8 + (row & 7)];
                    FoutD[row] = gam * (accp[rt][g] / l_run[rt][g]) + ident;
                }
        }
    }
}

extern "C" __global__ __launch_bounds__(256, 3)
void flash_kernel(const _Float16* __restrict__ xb2, const _Float16* __restrict__ xb3,
                  const _Float16* __restrict__ xb4,
                  const _Float16* __restrict__ V3, const _Float16* __restrict__ V4,
                  _Float16* __restrict__ Wg, float* __restrict__ Sml,
                  float* __restrict__ F3, float* __restrict__ F4d,
                  const float* __restrict__ g3, const float* __restrict__ g4)
{
    __shared__ _Float16 SB[32 * 512];           // 4 buffers x 8 frags = 32 KB
    __shared__ _Float16 SW[4 * 4 * 512];
    _Float16* SWw = &SW[(threadIdx.x >> 6) * 4 * 512];
    int bid = blockIdx.x;
    // c3 first (256 t-iters/block = longest), then c2, then c4 (tail).
    if (bid < 128) {                        // c3: MODE 1, 8 rb x 16 b
        int t = bid, x = t & 7, u = t >> 3;         // u in [0,16)
        int b = x + 8 * (u & 1), rb = u >> 1;       // rb in [0,8)
        flashT<1024, 1024, 8, 1, 2>(xb3 + (size_t)b * 1024 * 1024, V3 + (size_t)b * 16 * 1024,
                                    F3 + (size_t)b * 1024 * 16, nullptr, nullptr, nullptr, g3,
                                    rb * 128, 0, SB, SWw);
    } else if (bid < 384) {                 // c2: MODE 3, 4 rb x 4 ds x 16 b
        int t = bid - 128, x = t & 7, u = t >> 3;   // u in [0,32)
        int b = x + 8 * (u & 1), unit = u >> 1;
        int rb = unit & 3, ds = unit >> 2;
        flashT<4096, 512, 1, 3, 2>(xb2 + (size_t)b * 512 * 4096, nullptr, nullptr, nullptr,
                                   Wg + (size_t)b * 262144, Sml + (size_t)b * 4096, nullptr,
                                   rb * 128, ds * 128, SB, SWw);
    } else {                                // c4: MODE 2, 16 rb x 16 b
        int t = bid - 384, x = t & 7, u = t >> 3;   // u in [0,32)
        int b = x + 8 * (u & 1), rb = u >> 1;       // rb in [0,16)
        flashT<256, 2048, 16, 2, 2>(xb4 + (size_t)b * 2048 * 256, V4 + (size_t)b * 16 * 2048,
                                    nullptr, F4d + (size_t)b * 2048, nullptr, nullptr, g4,
                                    rb * 128, 0, SB, SWw);
    }
}

// ---------------------------------------------------------------------------
// Stage 4: c2 deferred projection: F2 = g2*(softmax@V2)+V2 from Wg + stats.
// ---------------------------------------------------------------------------
extern "C" __global__ __launch_bounds__(256)
void proj_c2_kernel(const _Float16* __restrict__ Wg, const float* __restrict__ Sml,
                    const _Float16* __restrict__ V2, const float* __restrict__ g2,
                    float* __restrict__ F2)
{
    int b = blockIdx.x >> 2, rb = blockIdx.x & 3;
    int lane = threadIdx.x & 63, wave = threadIdx.x >> 6;
    int l16 = lane & 15, quad = lane >> 4;
    size_t loff = (size_t)lane * 8;
    const _Float16* Wb = Wg + (size_t)b * 262144;
    const float* Sb = Sml + (size_t)b * 4096;
    const _Float16* Vb = V2 + (size_t)b * 96 * 512;
    const f4 fz = {0.f, 0.f, 0.f, 0.f};
    f4 accP[2][6];
    float M[2][4], L[2][4];
#pragma unroll
    for (int rt = 0; rt < 2; ++rt) {
#pragma unroll
        for (int pt = 0; pt < 6; ++pt) accP[rt][pt] = fz;
#pragma unroll
        for (int g = 0; g < 4; ++g) { M[rt][g] = -3.0e38f; L[rt][g] = 0.f; }
    }
    for (int t = 0; t < 4; ++t) {
        f4 tmp[2][6];
#pragma unroll
        for (int rt = 0; rt < 2; ++rt)
#pragma unroll
            for (int pt = 0; pt < 6; ++pt) tmp[rt][pt] = fz;
#pragma unroll
        for (int kb = 0; kb < 4; ++kb) {
            h8 wa[2];
#pragma unroll
            for (int rt = 0; rt < 2; ++rt) {
                int rfrag = rb * 8 + wave * 2 + rt;
                wa[rt] = *(const h8*)&Wb[((size_t)((t * 32 + rfrag) * 4 + kb) << 9) + loff];
            }
#pragma unroll
            for (int pt = 0; pt < 6; ++pt) {
                h8 vb = *(const h8*)&Vb[((size_t)(pt * 16 + t * 4 + kb) << 9) + loff];
#pragma unroll
                for (int rt = 0; rt < 2; ++rt)
                    tmp[rt][pt] = __builtin_amdgcn_mfma_f32_16x16x32_f16(wa[rt], vb, tmp[rt][pt], 0, 0, 0);
            }
        }
#pragma unroll
        for (int rt = 0; rt < 2; ++rt)
#pragma unroll
            for (int g = 0; g < 4; ++g) {
                int row = (rb * 8 + wave * 2 + rt) * 16 + quad * 4 + g;
                float mt = Sb[((size_t)t * 512 + row) * 2 + 0];
                float lt = Sb[((size_t)t * 512 + row) * 2 + 1];
                float nm = fmaxf(M[rt][g], mt);
                float ao = __expf(M[rt][g] - nm);
                float at = __expf(mt - nm);
#pragma unroll
                for (int pt = 0; pt < 6; ++pt)
                    accP[rt][pt][g] = accP[rt][pt][g] * ao + at * tmp[rt][pt][g];
                L[rt][g] = L[rt][g] * ao + at * lt;
                M[rt][g] = nm;
            }
    }
    float gam = g2[0];
#pragma unroll
    for (int rt = 0; rt < 2; ++rt)
#pragma unroll
        for (int pt = 0; pt < 6; ++pt)
#pragma unroll
            for (int g = 0; g < 4; ++g) {
                int row = (rb * 8 + wave * 2 + rt) * 16 + quad * 4 + g;
                int p = pt * 16 + l16;
                float ident = (float)Vb[((size_t)pt * 16 + (row >> 5)) * 512
                               + (size_t)(((row >> 3) & 3) * 16 + (p & 15)) * 8 + (row & 7)];
                F2[((size_t)b * 512 + row) * 96 + p] = gam * (accP[rt][pt][g] / L[rt][g]) + ident;
            }
}

// ---------------------------------------------------------------------------
// Stage 5: gather activations into B-frag fp16 tensors for epilogue GEMMs.
// ---------------------------------------------------------------------------
extern "C" __global__ __launch_bounds__(256)
void gather1_kernel(const float* __restrict__ F2, const float* __restrict__ F3,
                    const float* __restrict__ V4d, const float* __restrict__ F4d,
                    _Float16* __restrict__ G, _Float16* __restrict__ XB3,
                    _Float16* __restrict__ XB4)
{
    int gid = blockIdx.x * 256 + threadIdx.x;
    int lane = gid & 63, fragid = gid >> 6;
    int kq = lane >> 4, n16 = lane & 15;
    _Float16 v[8];
    if (fragid < 1296) {                    // G[(i,k2)][(b,kcol)]
        int nb = fragid / 144, kb = fragid - nb * 144;
        int n = nb * 16 + n16;
        int b = n / 9, kcol = n - b * 9;
        int kh = kcol / 3, kw = kcol - kh * 3;
#pragma unroll
        for (int j = 0; j < 8; ++j) {
            int K = kb * 32 + kq * 8 + j;
            int i = K / 9, k2 = K - i * 9;
            int kh2 = k2 / 3, kw2 = k2 - kh2 * 3;
            int p = (kh * 3 + kh2) * 9 + kw * 3 + kw2;
            v[j] = (_Float16)F2[((size_t)b * 512 + i) * 96 + p];
        }
        *(h8*)&G[((size_t)fragid << 9) + lane * 8] = *(h8*)v;
    } else if (fragid < 1584) {             // XB3[(i,k)][b]
        int kb = fragid - 1296;
#pragma unroll
        for (int j = 0; j < 8; ++j) {
            int K = kb * 32 + kq * 8 + j;
            int i = K / 9, k9 = K - i * 9;
            v[j] = (_Float16)F3[((size_t)n16 * 1024 + i) * 16 + k9];
        }
        *(h8*)&XB3[((size_t)kb << 9) + lane * 8] = *(h8*)v;
    } else {                                // XB4[i][(b,which)]
        int f = fragid - 1584;
        int nb = f >> 6, kb = f & 63;
        const float* src = nb ? F4d : V4d;
#pragma unroll
        for (int j = 0; j < 8; ++j) {
            int i = kb * 32 + kq * 8 + j;
            v[j] = (_Float16)src[(size_t)n16 * 2048 + i];
        }
        *(h8*)&XB4[((size_t)f << 9) + lane * 8] = *(h8*)v;
    }
}

// gather XB2 from V2m split partials (fused 9-way reduce)
extern "C" __global__ __launch_bounds__(256)
void gather2_kernel(const float* __restrict__ Pv, _Float16* __restrict__ XB2)
{
    int gid = blockIdx.x * 256 + threadIdx.x;   // 144 frags x 64 lanes
    int lane = gid & 63, kb = gid >> 6;
    int kq = lane >> 4, b = lane & 15;
    _Float16 v[8];
#pragma unroll
    for (int j = 0; j < 8; ++j) {
        int K = kb * 32 + kq * 8 + j;
        int jj = K / 9, k = K - jj * 9;
        float s = 0.f;
#pragma unroll
        for (int ss = 0; ss < 9; ++ss)
            s += Pv[((size_t)ss * 8192 + (size_t)b * 512 + jj) * 9 + k];
        v[j] = (_Float16)s;
    }
    *(h8*)&XB2[((size_t)kb << 9) + lane * 8] = *(h8*)v;
}

// ---------------------------------------------------------------------------
// Stage 6: epilogue GEMMs (MFMA), split-K for occupancy.
// ---------------------------------------------------------------------------
extern "C" __global__ __launch_bounds__(256)
void ep_gemm1_kernel(const _Float16* __restrict__ w2af, const _Float16* __restrict__ G,
                     const _Float16* __restrict__ w3f, const _Float16* __restrict__ XB3,
                     const _Float16* __restrict__ w4f, const _Float16* __restrict__ XB4,
                     float* __restrict__ Pv, float* __restrict__ Pr3,
                     float* __restrict__ Pr4)
{
    int lane = threadIdx.x & 63, wave = threadIdx.x >> 6;
    int l16 = lane & 15, quad = lane >> 4;
    size_t loff = (size_t)lane * 8;
    const f4 fz = {0.f, 0.f, 0.f, 0.f};
    int bid = blockIdx.x;
    if (bid < 72) {                         // V2m partials: 32 mt x 9 splits
        int unit = bid * 4 + wave;          // [0,288)
        int mt = unit & 31, s = unit >> 5;
        f4 acc[9];
#pragma unroll
        for (int nb = 0; nb < 9; ++nb) acc[nb] = fz;
#pragma unroll 2
        for (int kf = s * 16; kf < s * 16 + 16; ++kf) {
            h8 a = *(const h8*)&w2af[(((size_t)(mt * 144 + kf)) << 9) + loff];
#pragma unroll
            for (int nb = 0; nb < 9; ++nb) {
                h8 bfr = *(const h8*)&G[(((size_t)(nb * 144 + kf)) << 9) + loff];
                acc[nb] = __builtin_amdgcn_mfma_f32_16x16x32_f16(a, bfr, acc[nb], 0, 0, 0);
            }
        }
#pragma unroll
        for (int nb = 0; nb < 9; ++nb)
#pragma unroll
            for (int g = 0; g < 4; ++g) {
                int j = mt * 16 + quad * 4 + g;
                int n = nb * 16 + l16;
                int b = n / 9, k = n - b * 9;
                Pv[((size_t)s * 8192 + (size_t)b * 512 + j) * 9 + k] = acc[nb][g];
            }
    } else if (bid < 216) {                 // raw3 partials: 32 mt x 18 splits
        int unit = (bid - 72) * 4 + wave;   // [0,576)
        int mt = unit & 31, s = unit >> 5;
        f4 acc = fz;
#pragma unroll 4
        for (int kf = s * 16; kf < s * 16 + 16; ++kf) {
            h8 a = *(const h8*)&w3f[(((size_t)(mt * 288 + kf)) << 9) + loff];
            h8 bfr = *(const h8*)&XB3[((size_t)kf << 9) + loff];
            acc = __builtin_amdgcn_mfma_f32_16x16x32_f16(a, bfr, acc, 0, 0, 0);
        }
#pragma unroll
        for (int g = 0; g < 4; ++g)
            Pr3[(size_t)(s * 512 + mt * 16 + quad * 4 + g) * 16 + l16] = acc[g];
    } else {                                // raw4 partials: 32 mt x 8 splits
        int unit = (bid - 216) * 4 + wave;  // [0,256)
        int mt = unit & 31, s = unit >> 5;
        f4 acc[2] = {fz, fz};
#pragma unroll 2
        for (int kf = s * 8; kf < s * 8 + 8; ++kf) {
            h8 a = *(const h8*)&w4f[(((size_t)(mt * 64 + kf)) << 9) + loff];
#pragma unroll
            for (int nb = 0; nb < 2; ++nb) {
                h8 bfr = *(const h8*)&XB4[(((size_t)(nb * 64 + kf)) << 9) + loff];
                acc[nb] = __builtin_amdgcn_mfma_f32_16x16x32_f16(a, bfr, acc[nb], 0, 0, 0);
            }
        }
#pragma unroll
        for (int nb = 0; nb < 2; ++nb)
#pragma unroll
            for (int g = 0; g < 4; ++g)
                Pr4[((size_t)s * 1024 + (size_t)nb * 512 + mt * 16 + quad * 4 + g) * 16 + l16] = acc[nb][g];
    }
}

extern "C" __global__ __launch_bounds__(256)
void ep_gemm2_kernel(const _Float16* __restrict__ w2bf, const _Float16* __restrict__ XB2,
                     float* __restrict__ Pr2)
{
    int lane = threadIdx.x & 63, wave = threadIdx.x >> 6;
    int l16 = lane & 15, quad = lane >> 4;
    size_t loff = (size_t)lane * 8;
    int unit = blockIdx.x * 4 + wave;       // [0,288): 32 mt x 9 splits
    int mt = unit & 31, s = unit >> 5;
    f4 acc = {0.f, 0.f, 0.f, 0.f};
#pragma unroll 4
    for (int kf = s * 16; kf < s * 16 + 16; ++kf) {
        h8 a = *(const h8*)&w2bf[(((size_t)(mt * 144 + kf)) << 9) + loff];
        h8 bfr = *(const h8*)&XB2[((size_t)kf << 9) + loff];
        acc = __builtin_amdgcn_mfma_f32_16x16x32_f16(a, bfr, acc, 0, 0, 0);
    }
#pragma unroll
    for (int g = 0; g < 4; ++g)
        Pr2[(size_t)(s * 512 + mt * 16 + quad * 4 + g) * 16 + l16] = acc[g];
}

// ---------------------------------------------------------------------------
// Stage 7: PF assembly (sums split partials) + FC, fused.
// ---------------------------------------------------------------------------
extern "C" __global__ __launch_bounds__(256)
void final_kernel(const float* __restrict__ Pr2, const float* __restrict__ Pr3,
                  const float* __restrict__ Pr4, const float* __restrict__ V4d,
                  const float* __restrict__ b4, const float* __restrict__ b2b,
                  const float* __restrict__ fcw, const float* __restrict__ fcb,
                  float* __restrict__ out)
{
    __shared__ float pf[3584];
    __shared__ float r0s[256], r1s[256];
    int b = blockIdx.x, tid = threadIdx.x;
    for (int o = tid; o < 512; o += 256) {
        float pd = 0.f, pa = 0.f;
#pragma unroll
        for (int s = 0; s < 8; ++s) {
            pd += Pr4[(size_t)(s * 1024 + o) * 16 + b];
            pa += Pr4[(size_t)(s * 1024 + 512 + o) * 16 + b];
        }
        float r3 = 0.f;
#pragma unroll
        for (int s = 0; s < 18; ++s) r3 += Pr3[(size_t)(s * 512 + o) * 16 + b];
        float r2 = 0.f;
#pragma unroll
        for (int s = 0; s < 9; ++s) r2 += Pr2[(size_t)(s * 512 + o) * 16 + b];
        float pd4 = pd + b4[o];
        pf[1024 + o] = pa + b4[o] + pd4;
        pf[512 + o] = r3 * (1.f / 256.f) + pd4;
        pf[o] = r2 * (1.f / 256.f) + b2b[o] + pd4;
    }
    for (int i = tid; i < 2048; i += 256) pf[1536 + i] = V4d[(size_t)b * 2048 + i];
    __syncthreads();
    float p0 = 0.f, p1 = 0.f;
    for (int k = tid; k < 3584; k += 256) {
        float f = pf[k];
        p0 += fcw[k] * f;
        p1 += fcw[3584 + k] * f;
    }
    r0s[tid] = p0;
    r1s[tid] = p1;
    __syncthreads();
    for (int s = 128; s > 0; s >>= 1) {
        if (tid < s) { r0s[tid] += r0s[tid + s]; r1s[tid] += r1s[tid + s]; }
        __syncthreads();
    }
    if (tid == 0) {
        out[b * 2 + 0] = r0s[0] + fcb[0];
        out[b * 2 + 1] = r1s[0] + fcb[1];
    }
}

// ---------------------------------------------------------------------------

extern "C" void kernel_launch(void* const* d_in, const int* in_sizes, int n_in,
                              void* d_out, int out_size, void* d_ws, size_t ws_size,
                              hipStream_t stream)
{
    const float* c2 = (const float*)d_in[0];
    const float* c3 = (const float*)d_in[1];
    const float* c4 = (const float*)d_in[2];
    const float* w4 = (const float*)d_in[3];
    const float* b4 = (const float*)d_in[4];
    const float* w3 = (const float*)d_in[5];
    const float* w2a = (const float*)d_in[6];
    const float* w2b = (const float*)d_in[7];
    const float* b2b = (const float*)d_in[8];
    const float* g2 = (const float*)d_in[9];
    const float* g3 = (const float*)d_in[10];
    const float* g4 = (const float*)d_in[11];
    const float* fcw = (const float*)d_in[12];
    const float* fcb = (const float*)d_in[13];
    float* out = (float*)d_out;

    char* ws = (char*)d_ws;
    size_t off = 0;
    auto carve = [&](size_t bytes) -> char* {
        char* p = ws + off;
        off += (bytes + 255) & ~(size_t)255;
        return p;
    };
    _Float16* xb2 = (_Float16*)carve(67108864);
    _Float16* xb3 = (_Float16*)carve(33554432);
    _Float16* xb4 = (_Float16*)carve(16777216);
    _Float16* V2 = (_Float16*)carve(1572864);
    _Float16* V3 = (_Float16*)carve(524288);
    _Float16* V4 = (_Float16*)carve(1048576);
    float* V4d = (float*)carve(131072);
    _Float16* Wg = (_Float16*)carve(8388608);
    float* Sml = (float*)carve(262144);
    float* F3 = (float*)carve(1048576);
    float* F4d = (float*)carve(131072);
    if (ws_size < off) return;  // workspace too small: fail visibly, no OOB

    // post-flash buffers alias the (then-dead) xb2 region (~31 MB < 64 MB)
    char* al = (char*)xb2;
    auto sub = [&](size_t bytes) -> char* {
        char* p = al;
        al += (bytes + 255) & ~(size_t)255;
        return p;
    };
    float* F2 = (float*)sub(3145728);
    _Float16* w4f = (_Float16*)sub(2097152);
    _Float16* w3f = (_Float16*)sub(9437184);
    _Float16* w2af = (_Float16*)sub(4718592);
    _Float16* w2bf = (_Float16*)sub(4718592);
    _Float16* G = (_Float16*)sub(1327104);
    _Float16* XB3 = (_Float16*)sub(294912);
    _Float16* XB4 = (_Float16*)sub(131072);
    float* Pv = (float*)sub(2654208);
    _Float16* XB2 = (_Float16*)sub(147456);
    float* Pr2 = (float*)sub(294912);
    float* Pr3 = (float*)sub(589824);
    float* Pr4 = (float*)sub(524288);

    repack_kernel<<<14336, 256, 0, stream>>>(c2, c3, c4, xb2, xb3, xb4);
    func_c2_kernel<<<2048, 256, 0, stream>>>(c2, V2);
    func_c3_kernel<<<4096, 256, 0, stream>>>(c3, V3);
    func_c4_kernel<<<8192, 256, 0, stream>>>(c4, V4, V4d);
    flash_kernel<<<640, 256, 0, stream>>>(xb2, xb3, xb4, V3, V4, Wg, Sml,
                                          F3, F4d, g3, g4);
    repack_w_kernel<<<2560, 256, 0, stream>>>(w4, w3, w2a, w2b, w4f, w3f, w2af, w2bf);
    proj_c2_kernel<<<64, 256, 0, stream>>>(Wg, Sml, V2, g2, F2);
    gather1_kernel<<<428, 256, 0, stream>>>(F2, F3, V4d, F4d, G, XB3, XB4);
    ep_gemm1_kernel<<<280, 256, 0, stream>>>(w2af, G, w3f, XB3, w4f, XB4,
                                             Pv, Pr3, Pr4);
    gather2_kernel<<<36, 256, 0, stream>>>(Pv, XB2);
    ep_gemm2_kernel<<<72, 256, 0, stream>>>(w2bf, XB2, Pr2);
    final_kernel<<<16, 256, 0, stream>>>(Pr2, Pr3, Pr4, V4d, b4, b2b,
                                         fcw, fcb, out);
}